// Round 6
// baseline (171.665 us; speedup 1.0000x reference)
//
#include <hip/hip_runtime.h>
#include <cstdint>

typedef float    f32x4 __attribute__((ext_vector_type(4)));
typedef _Float16 f16x8 __attribute__((ext_vector_type(8)));
typedef unsigned int uint32;

// ---------------------------------------------------------------------------
// Workspace (ushort units): two fp16[256][256] arrays (RNE, alpha folded in)
//   [0]      Wn[i][j] = f16(0.5*W[i][j])   (A-operand for Xv update)
//   [65536]  Wt[j][i] = f16(0.5*W[i][j])   (A-operand for Xh update)
// ---------------------------------------------------------------------------

__global__ void HAM_prep_w(const float* __restrict__ W, unsigned short* __restrict__ ws)
{
    int idx = blockIdx.x * 256 + threadIdx.x;          // 0 .. 65535
    int i = idx >> 8, j = idx & 255;
    _Float16 h = (_Float16)(0.5f * W[idx]);            // RNE, rel err <= 2^-12
    unsigned short hb = __builtin_bit_cast(unsigned short, h);
    ws[idx] = hb;
    ws[65536 + j*256 + i] = hb;
}

__device__ __forceinline__ float fast_tanh(float x)
{
    float e = __expf(2.0f * x);
    return 1.0f - __fdividef(2.0f, e + 1.0f);
}

// ---------------------------------------------------------------------------
// 512 threads = 8 waves; block owns 32 batch rows (acc[4][2] -> 32 VGPRs,
// total demand ~200 <= 256 cap: NO spill, unlike batch-64's ~230+).
// Waves 0-3: Xv 64-feat strips; waves 4-7: Xh. W (fp16) strip in 128 VGPRs
// for all iterations; NO global loads inside the iteration loop.
// g (fp16) double-buffered in LDS (2 x 32 KiB) -> ONE barrier per iteration:
//   phase1: write g[it&1] (own strip) | barrier | phase2: read g[it&1] (other)
// Race-free: phase1(it+1) writes buf[(it+1)&1]; slowest wave in phase2(it)
// reads buf[it&1] — different buffers.
// Swizzle: XOR (li<<4) on the FULL byte offset (bijective per 512B row,
// preserves 8B/16B alignment; residual 2-way conflict is free per m136).
// ---------------------------------------------------------------------------

__launch_bounds__(512, 2)
__global__ void HAM_main(const float* __restrict__ xv_in, const float* __restrict__ xh_in,
                         const unsigned short* __restrict__ wsp, const int* __restrict__ miter,
                         float* __restrict__ out)
{
    extern __shared__ char smem[];   // 64 KiB: buf0{gv|gh} buf1{gv|gh}, 16 KiB halves
    const int tid  = threadIdx.x;
    const int wid  = tid >> 6;
    const int lane = tid & 63;
    const int li   = lane & 15;      // MFMA m/n index within tile
    const int g    = lane >> 4;      // quarter-wave group (k-chunk)
    const bool isV = (wid < 4);
    const int fbase = (wid & 3) * 64;
    const long b0 = (long)blockIdx.x * 32;

    const float* xin = isV ? xv_in : xh_in;
    const unsigned short* aP = wsp + (isV ? 0 : 65536);
    const int wrHalf = isV ? 0 : 16384;      // my g goes here (within a buffer)
    const int rdHalf = isV ? 16384 : 0;      // my GEMM consumes the other half

    // ---- preload W strip into registers (128 VGPRs, reused every iter) ----
    f16x8 aW[4][8];
    #pragma unroll
    for (int mt = 0; mt < 4; ++mt) {
        const unsigned short* rp = aP + (fbase + mt*16 + li)*256 + g*8;
        #pragma unroll
        for (int kt = 0; kt < 8; ++kt)
            aW[mt][kt] = *(const f16x8*)(rp + kt*32);   // ushort-unit offsets
    }

    // ---- load initial state into accumulators (D-layout) ----
    f32x4 acc[4][2];
    #pragma unroll
    for (int mt = 0; mt < 4; ++mt)
        #pragma unroll
        for (int nt = 0; nt < 2; ++nt) {
            long b = b0 + nt*16 + li;
            int  f = fbase + mt*16 + g*4;
            acc[mt][nt] = *(const f32x4*)(xin + b*256 + f);
        }

    const int iters = *miter;

    for (int it = 0; it < iters; ++it) {
        char* buf = smem + (it & 1) * 32768;
        char* wr  = buf + wrHalf;
        char* rd  = buf + rdHalf;

        // ---- phase 1: g = tanh(x) -> fp16 pairs (cvt_pkrtz) -> LDS ----
        #pragma unroll
        for (int mt = 0; mt < 4; ++mt) {
            #pragma unroll
            for (int nt = 0; nt < 2; ++nt) {
                float t0 = fast_tanh(acc[mt][nt][0]);
                float t1 = fast_tanh(acc[mt][nt][1]);
                float t2 = fast_tanh(acc[mt][nt][2]);
                float t3 = fast_tanh(acc[mt][nt][3]);
                uint32 u01 = __builtin_bit_cast(uint32, __builtin_amdgcn_cvt_pkrtz(t0, t1));
                uint32 u23 = __builtin_bit_cast(uint32, __builtin_amdgcn_cvt_pkrtz(t2, t3));
                int off = (((nt*16 + li) * 512) + (fbase + mt*16 + g*4) * 2) ^ (li << 4);
                *(uint2*)(wr + off) = make_uint2(u01, u23);
            }
        }
        __syncthreads();

        // ---- phase 2: x_new = 0.5*x + g_other * (0.5*W) ----
        #pragma unroll
        for (int mt = 0; mt < 4; ++mt)
            #pragma unroll
            for (int nt = 0; nt < 2; ++nt)
                acc[mt][nt] *= 0.5f;

        #pragma unroll
        for (int kt = 0; kt < 8; ++kt) {
            #pragma unroll
            for (int nt = 0; nt < 2; ++nt) {
                int off = (((nt*16 + li) * 512) + kt*64 + g*16) ^ (li << 4);
                f16x8 bH = *(const f16x8*)(rd + off);
                #pragma unroll
                for (int mt = 0; mt < 4; ++mt)
                    acc[mt][nt] = __builtin_amdgcn_mfma_f32_16x16x32_f16(aW[mt][kt], bH, acc[mt][nt], 0, 0, 0);
            }
        }
        // no trailing barrier: next phase-1 writes the OTHER buffer
    }

    // ---- epilogue: out[b] = [tanh(xv), tanh(xh)] ----
    const int colBase = (isV ? 0 : 256) + fbase;
    #pragma unroll
    for (int mt = 0; mt < 4; ++mt) {
        #pragma unroll
        for (int nt = 0; nt < 2; ++nt) {
            long b = b0 + nt*16 + li;
            f32x4 o;
            #pragma unroll
            for (int j = 0; j < 4; ++j) o[j] = fast_tanh(acc[mt][nt][j]);
            *(f32x4*)(out + b*512 + colBase + mt*16 + g*4) = o;
        }
    }
}

extern "C" void kernel_launch(void* const* d_in, const int* in_sizes, int n_in,
                              void* d_out, int out_size, void* d_ws, size_t ws_size,
                              hipStream_t stream)
{
    const float* xv   = (const float*)d_in[0];
    const float* xh   = (const float*)d_in[1];
    const float* W    = (const float*)d_in[2];
    const int* miter  = (const int*)d_in[3];
    float* out        = (float*)d_out;
    unsigned short* ws = (unsigned short*)d_ws;

    const int B = in_sizes[0] / 256;        // 32768

    HAM_prep_w<<<256, 256, 0, stream>>>(W, ws);

    (void)hipFuncSetAttribute((const void*)HAM_main,
                              hipFuncAttributeMaxDynamicSharedMemorySize, 65536);
    HAM_main<<<B / 32, 512, 65536, stream>>>(xv, xh, ws, miter, out);
}